// Round 13
// baseline (183.596 us; speedup 1.0000x reference)
//
#include <hip/hip_runtime.h>
#include <hip/hip_bf16.h>

// MultiHeadAttention: B=2,S=2048,D=1024,H=16,DK=DV=64, causal (key i <= query j).
// Reference quirk: softmax over the q-projection index i; output indexed by the
// k-projection index j  =>  attn-query := X@WK, attn-keys := (X@WQ)*0.125,
// attn-values := X@WV, causal flash attention over i<=j, then @WO + bO.
// Proven dtype model: inputs fp32, output fp32, bf16 intermediates OK.
//
// Round-13: attn was ~76% LDS-issue-bound (312 LDS-cyc/wave/tile: every wave
// re-read full K/V tiles from LDS; bank conflicts 0, pipes all <25%). attn_v5
// loads K/V MFMA fragments DIRECTLY global->register (tiles are L1/L2-hot),
// keeps only per-wave P in LDS (120 cyc/wave/tile), and drops ALL barriers
// (no cross-wave LDS left). Same fragment math, same balanced qblk map.
// Prologue: cvt + 4x weight-transpose merged into one kernel.

typedef __bf16 bf16;
typedef __bf16 bf16x8 __attribute__((ext_vector_type(8)));
typedef __bf16 bf16x4 __attribute__((ext_vector_type(4)));
typedef float  f32x4  __attribute__((ext_vector_type(4)));

constexpr int Sq = 2048;
constexpr int Dm = 1024;
constexpr int Hh = 16;

// K scale: 1/sqrt(DK) * log2(e), so softmax is p = 2^s via v_exp_f32.
#define KSCALE 0.18033688011112042f

// global -> LDS direct copy, 16B per lane, wave-uniform LDS base + lane*16.
static __device__ __forceinline__ void gload_lds16(const bf16* g, bf16* l) {
  __builtin_amdgcn_global_load_lds(
      (const __attribute__((address_space(1))) unsigned int*)g,
      (__attribute__((address_space(3))) unsigned int*)l, 16, 0, 0);
}

// ---------------------------------------------------------------------------
// Merged prologue: bx<2048 -> fp32->bf16 convert of inputs (8 elems/thread);
// else 64x64 transpose tiles of WQ/WK/WV/WO -> Wt (bf16).
__global__ __launch_bounds__(256) void prep(
    const float* __restrict__ inputs,
    const float* __restrict__ WQ, const float* __restrict__ WK,
    const float* __restrict__ WV, const float* __restrict__ WO,
    bf16* __restrict__ Xin, bf16* __restrict__ Wt) {
  __shared__ bf16 t[64][65];
  const int bx = blockIdx.x;
  const int tid = threadIdx.x;
  if (bx < 2048) {
    const int i = (bx * 256 + tid) * 8;
    float4 a = *reinterpret_cast<const float4*>(inputs + i);
    float4 b = *reinterpret_cast<const float4*>(inputs + i + 4);
    bf16x8 o;
    o[0] = (bf16)a.x; o[1] = (bf16)a.y; o[2] = (bf16)a.z; o[3] = (bf16)a.w;
    o[4] = (bf16)b.x; o[5] = (bf16)b.y; o[6] = (bf16)b.z; o[7] = (bf16)b.w;
    *reinterpret_cast<bf16x8*>(Xin + i) = o;
    return;
  }
  const int rr0 = bx - 2048;            // 0..1023
  const int z = rr0 >> 8;               // weight index
  const int tt = rr0 & 255;
  const int r0 = (tt >> 4) * 64, c0 = (tt & 15) * 64;
  const float* in = (z == 0) ? WQ : (z == 1) ? WK : (z == 2) ? WV : WO;
  bf16* op = Wt + (size_t)z * 1024 * 1024;
  const int rr = tid >> 3, cc = (tid & 7) * 8;
#pragma unroll
  for (int it = 0; it < 2; ++it) {
    int row = rr + it * 32;
    const float* ip = in + (size_t)(r0 + row) * 1024 + c0 + cc;
    float4 a = *reinterpret_cast<const float4*>(ip);
    float4 b = *reinterpret_cast<const float4*>(ip + 4);
    t[row][cc + 0] = (bf16)a.x; t[row][cc + 1] = (bf16)a.y;
    t[row][cc + 2] = (bf16)a.z; t[row][cc + 3] = (bf16)a.w;
    t[row][cc + 4] = (bf16)b.x; t[row][cc + 5] = (bf16)b.y;
    t[row][cc + 6] = (bf16)b.z; t[row][cc + 7] = (bf16)b.w;
  }
  __syncthreads();
#pragma unroll
  for (int it = 0; it < 2; ++it) {
    int crow = rr + it * 32;
    alignas(16) bf16 o[8];
#pragma unroll
    for (int e = 0; e < 8; ++e) o[e] = t[cc + e][crow];
    *reinterpret_cast<bf16x8*>(op + (size_t)(c0 + crow) * 1024 + r0 + cc) =
        *reinterpret_cast<bf16x8*>(o);
  }
}

// ---------------------------------------------------------------------------
// MTx128 bf16 MFMA GEMM (MT=128 or 64), BK=64, 4 waves (2x2).
// Staging: global_load_lds, linear LDS dest, pre-swizzled global source
// => LDS[row][x] = G[row][x^(row&7)]; reads use matching XOR -> 0 conflicts.
// EPI 0: scatter Katt(=q*KSCALE)/Qatt(=k) [bh][s][64]; VattT [bh][dv][S] packed.
// EPI 1: Cout[m][n] = acc + bOf[n] (fp32 out).
template <int EPI, int MT>
__global__ __launch_bounds__(256) void gemm128(
    const bf16* __restrict__ A, const bf16* __restrict__ Bt,
    const int M, const int N, const int K,
    bf16* __restrict__ Katt, bf16* __restrict__ Qatt, bf16* __restrict__ VattT,
    const float* __restrict__ bOf, float* __restrict__ Cout) {
  constexpr int MF = MT / 32;  // M-frags per wave (wr covers MT/2 rows)
  __shared__ bf16 As[MT * 64], Bs[8192];
  const int tid = threadIdx.x;
  const int lane = tid & 63;
  const int w = tid >> 6;
  const int wr = w >> 1, wc = w & 1;
  const int g = lane >> 4, c = lane & 15;
  const int m0 = blockIdx.y * MT, n0 = blockIdx.x * 128;
  const int sr = lane >> 3;                    // row within 8-row group
  const int scp = ((lane & 7) ^ sr) * 8;       // pre-swizzled source chunk

  f32x4 acc[MF][4];
#pragma unroll
  for (int i = 0; i < MF; ++i)
#pragma unroll
    for (int j = 0; j < 4; ++j) acc[i][j] = f32x4{0.f, 0.f, 0.f, 0.f};

  for (int k0 = 0; k0 < K; k0 += 64) {
#pragma unroll
    for (int p = 0; p < MT / 32; ++p) {
      const int rowb = p * 32 + w * 8;  // rowb%8==0 -> staged row&7 == sr
      gload_lds16(A + (size_t)(m0 + rowb + sr) * K + k0 + scp, &As[rowb * 64]);
    }
#pragma unroll
    for (int p = 0; p < 4; ++p) {
      const int rowb = p * 32 + w * 8;
      gload_lds16(Bt + (size_t)(n0 + rowb + sr) * K + k0 + scp, &Bs[rowb * 64]);
    }
    __syncthreads();  // drains vmcnt(0) before barrier -> tiles visible
#pragma unroll
    for (int kk = 0; kk < 2; ++kk) {
      const int ch = kk * 4 + g;
      bf16x8 af[MF], bfr[4];
#pragma unroll
      for (int mf = 0; mf < MF; ++mf) {
        const int row = wr * (MT / 2) + mf * 16 + c;
        af[mf] = *reinterpret_cast<const bf16x8*>(
            &As[row * 64 + ((ch ^ (row & 7)) << 3)]);
      }
#pragma unroll
      for (int nf = 0; nf < 4; ++nf) {
        const int row = wc * 64 + nf * 16 + c;
        bfr[nf] = *reinterpret_cast<const bf16x8*>(
            &Bs[row * 64 + ((ch ^ (row & 7)) << 3)]);
      }
#pragma unroll
      for (int mf = 0; mf < MF; ++mf)
#pragma unroll
        for (int nf = 0; nf < 4; ++nf)
          acc[mf][nf] = __builtin_amdgcn_mfma_f32_16x16x32_bf16(
              af[mf], bfr[nf], acc[mf][nf], 0, 0, 0);
    }
    __syncthreads();
  }

#pragma unroll
  for (int mf = 0; mf < MF; ++mf)
#pragma unroll
    for (int nf = 0; nf < 4; ++nf) {
      const int n = n0 + wc * 64 + nf * 16 + c;
      const int mb = m0 + wr * (MT / 2) + mf * 16 + g * 4;
      if (EPI == 0 && n >= 2048) {
        bf16x4 pk;
#pragma unroll
        for (int r = 0; r < 4; ++r) pk[r] = (bf16)acc[mf][nf][r];
        const int b = mb >> 11, sb = mb & (Sq - 1);
        const int h = (n >> 6) & 15, dk = n & 63;
        *reinterpret_cast<bf16x4*>(
            &VattT[((size_t)(b * Hh + h) * 64 + dk) * Sq + sb]) = pk;
      } else {
#pragma unroll
        for (int r = 0; r < 4; ++r) {
          const int m = mb + r;
          float v = acc[mf][nf][r];
          if (EPI == 0) {
            const int b = m >> 11, s = m & (Sq - 1);
            const int h = (n >> 6) & 15, dk = n & 63;
            const int bh = b * Hh + h;
            if (n < 1024)
              Katt[((size_t)bh * Sq + s) * 64 + dk] = (bf16)(v * KSCALE);
            else
              Qatt[((size_t)bh * Sq + s) * 64 + dk] = (bf16)v;
          } else {
            Cout[(size_t)m * N + n] = v + bOf[n];
          }
        }
      }
    }
}

// ---------------------------------------------------------------------------
// Causal flash attention v5. Q/K: [bh][S][64] bf16, Vt: [bh][64][S] bf16.
// K/V fragments loaded DIRECTLY global->register (L1/L2-hot tiles); only the
// per-wave P goes through LDS (2KB/wave) -> NO barriers, 4 independent waves
// per block. No-max softmax (p=2^s), deferred l-reduce, balanced qblk map.
__global__ __launch_bounds__(256, 4) void attn_v5(
    const bf16* __restrict__ Q, const bf16* __restrict__ K,
    const bf16* __restrict__ Vt, bf16* __restrict__ X) {
  __shared__ bf16 Pb[4096];  // wave w owns [w*1024 .. w*1024+1024)
  const int tid = threadIdx.x, lane = tid & 63, w = tid >> 6;
  const int g = lane >> 4, c = lane & 15;
  const int bx = blockIdx.x;
  const int u = bx >> 5;                       // 0..31
  const int bh = bx & 31;                      // bh%8 == bx%8 -> 4 heads/XCD
  const int um = (u + 8 * (bh >> 3)) & 31;
  const int qblk = (um < 16) ? um : 47 - um;   // balanced bijection per bh
  const int b = bh >> 4, h = bh & 15;
  const size_t base = (size_t)bh * Sq * 64;
  const bf16* Kg = K + base;
  const bf16* Vg = Vt + (size_t)bh * 64 * Sq;
  bf16* Pw = Pb + w * 1024;

  // Q fragments from global (A-operand: row=c, k=kk*32+g*8+e)
  bf16x8 qf[2];
  {
    const bf16* Qg = Q + base + ((size_t)qblk * 64 + w * 16 + c) * 64;
    qf[0] = *reinterpret_cast<const bf16x8*>(Qg + g * 8);
    qf[1] = *reinterpret_cast<const bf16x8*>(Qg + 32 + g * 8);
  }

  f32x4 acc[4];
  float lpart[4] = {0.f, 0.f, 0.f, 0.f};
#pragma unroll
  for (int vg = 0; vg < 4; ++vg) acc[vg] = f32x4{0.f, 0.f, 0.f, 0.f};

  const int ntiles = qblk + 1;
  for (int t = 0; t < ntiles; ++t) {
    // K fragments straight from global: kf[kk][kg][e] = K[t*64+kg*16+c][kk*32+g*8+e]
    const bf16* Kt = Kg + (size_t)t * 64 * 64;
    bf16x8 kf[2][4];
#pragma unroll
    for (int kk = 0; kk < 2; ++kk)
#pragma unroll
      for (int kg = 0; kg < 4; ++kg)
        kf[kk][kg] = *reinterpret_cast<const bf16x8*>(
            Kt + (kg * 16 + c) * 64 + kk * 32 + g * 8);

    // S = Q K^T (rows = query, cols = key)
    f32x4 sc[4];
#pragma unroll
    for (int kg = 0; kg < 4; ++kg) sc[kg] = f32x4{0.f, 0.f, 0.f, 0.f};
#pragma unroll
    for (int kk = 0; kk < 2; ++kk)
#pragma unroll
      for (int kg = 0; kg < 4; ++kg)
        sc[kg] = __builtin_amdgcn_mfma_f32_16x16x32_bf16(
            qf[kk], kf[kk][kg], sc[kg], 0, 0, 0);

    // V fragments from global (issue early; latency hides under exp chain):
    // vf[ks][vg][e] = Vt[vg*16+c][t*64 + ks*32 + g*8 + e]
    bf16x8 vf[2][4];
#pragma unroll
    for (int ks = 0; ks < 2; ++ks)
#pragma unroll
      for (int vg = 0; vg < 4; ++vg)
        vf[ks][vg] = *reinterpret_cast<const bf16x8*>(
            Vg + (size_t)(vg * 16 + c) * Sq + t * 64 + ks * 32 + g * 8);

    // softmax-lite: p = 2^s, diag mask, P to per-wave LDS, partial row sums
    const bool diag = (t == qblk);
#pragma unroll
    for (int kg = 0; kg < 4; ++kg)
#pragma unroll
      for (int r = 0; r < 4; ++r) {
        float p = __builtin_amdgcn_exp2f(sc[kg][r]);
        if (diag) {
          const int i = kg * 16 + c;
          const int j = w * 16 + g * 4 + r;
          p = (i <= j) ? p : 0.f;
        }
        lpart[r] += p;
        const int prow = g * 4 + r, pcol = kg * 16 + c;
        Pw[prow * 64 + (((pcol >> 3) ^ (prow & 7)) << 3) + (pcol & 7)] = (bf16)p;
      }

    // O += P V (P from own-wave LDS region; same-wave DS ordering)
#pragma unroll
    for (int ks = 0; ks < 2; ++ks) {
      const int ch = ks * 4 + g;
      bf16x8 pf = *reinterpret_cast<const bf16x8*>(
          &Pw[c * 64 + ((ch ^ (c & 7)) << 3)]);
#pragma unroll
      for (int vg = 0; vg < 4; ++vg)
        acc[vg] = __builtin_amdgcn_mfma_f32_16x16x32_bf16(
            pf, vf[ks][vg], acc[vg], 0, 0, 0);
    }
  }

  // deferred l-reduction (once) and output
  float linv[4];
#pragma unroll
  for (int r = 0; r < 4; ++r) {
    float l = lpart[r];
    l += __shfl_xor(l, 1);
    l += __shfl_xor(l, 2);
    l += __shfl_xor(l, 4);
    l += __shfl_xor(l, 8);
    linv[r] = 1.f / l;
  }
#pragma unroll
  for (int vg = 0; vg < 4; ++vg)
#pragma unroll
    for (int r = 0; r < 4; ++r) {
      const int j = qblk * 64 + w * 16 + g * 4 + r;
      const int dv = vg * 16 + c;
      X[((size_t)b * Sq + j) * Dm + h * 64 + dv] = (bf16)(acc[vg][r] * linv[r]);
    }
}

// ---------------------------------------------------------------------------
extern "C" void kernel_launch(void* const* d_in, const int* in_sizes, int n_in,
                              void* d_out, int out_size, void* d_ws, size_t ws_size,
                              hipStream_t stream) {
  const float* inputs = (const float*)d_in[0];
  // d_in[1] = mask: structural causal triu, recomputed analytically (unused)
  const float* WQ = (const float*)d_in[2];
  const float* WK = (const float*)d_in[3];
  const float* WV = (const float*)d_in[4];
  const float* WO = (const float*)d_in[5];
  const float* bO = (const float*)d_in[6];
  float* out = (float*)d_out;

  bf16* Xin   = (bf16*)d_ws;               // [4096][1024]; reused as X later
  bf16* Wt    = Xin + 4096 * 1024;         // [4096][1024]: WQt,WKt,WVt,WOt
  bf16* Katt  = Wt + 4 * 1024 * 1024;      // [32][2048][64]  (= q-proj * KSCALE)
  bf16* Qatt  = Katt + (1 << 22);          // [32][2048][64]  (= k-proj)
  bf16* VattT = Qatt + (1 << 22);          // [32][64][2048]  (= v-proj, transposed)
  bf16* X     = Xin;                       // alias: Xin dead after QKV GEMM
  // ws use: 40 MiB

  prep<<<3072, 256, 0, stream>>>(inputs, WQ, WK, WV, WO, Xin, Wt);

  gemm128<0, 128><<<dim3(24, 32), 256, 0, stream>>>(
      Xin, Wt, 4096, 3072, 1024, Katt, Qatt, VattT, nullptr, nullptr);

  attn_v5<<<dim3(1024), 256, 0, stream>>>(Qatt, Katt, VattT, X);

  gemm128<1, 64><<<dim3(8, 64), 256, 0, stream>>>(
      X, Wt + 3 * 1024 * 1024, 4096, 1024, 1024,
      nullptr, nullptr, nullptr, bO, out);
}

// Round 14
// 103.743 us; speedup vs baseline: 1.7697x; 1.7697x over previous
//
#include <hip/hip_runtime.h>
#include <hip/hip_bf16.h>

// MultiHeadAttention: B=2,S=2048,D=1024,H=16,DK=DV=64, causal (key i <= query j).
// Reference quirk: softmax over the q-projection index i; output indexed by the
// k-projection index j  =>  attn-query := X@WK, attn-keys := (X@WQ)*0.125,
// attn-values := X@WV, causal flash attention over i<=j, then @WO + bO.
// Proven dtype model: inputs fp32, output fp32, bf16 intermediates OK.
//
// Round-14: revert r13's direct-global attn (127us: scattered 16-segment
// fragment loads swamped L1/TA). attn_v7 = r12's proven LDS-staged v4 with
// QBLK=128 and TWO query-subtiles per wave: kf/vf LDS reads amortize over 2x
// MFMA work (-31% LDS cycles/unit). Staging/prefetch/softmax code unchanged.

typedef __bf16 bf16;
typedef __bf16 bf16x8 __attribute__((ext_vector_type(8)));
typedef __bf16 bf16x4 __attribute__((ext_vector_type(4)));
typedef float  f32x4  __attribute__((ext_vector_type(4)));

constexpr int Sq = 2048;
constexpr int Dm = 1024;
constexpr int Hh = 16;

// K scale: 1/sqrt(DK) * log2(e), so softmax is p = 2^s via v_exp_f32.
#define KSCALE 0.18033688011112042f

// global -> LDS direct copy, 16B per lane, wave-uniform LDS base + lane*16.
static __device__ __forceinline__ void gload_lds16(const bf16* g, bf16* l) {
  __builtin_amdgcn_global_load_lds(
      (const __attribute__((address_space(1))) unsigned int*)g,
      (__attribute__((address_space(3))) unsigned int*)l, 16, 0, 0);
}

// ---------------------------------------------------------------------------
// Merged prologue: bx<2048 -> fp32->bf16 convert of inputs (8 elems/thread);
// else 64x64 transpose tiles of WQ/WK/WV/WO -> Wt (bf16).
__global__ __launch_bounds__(256) void prep(
    const float* __restrict__ inputs,
    const float* __restrict__ WQ, const float* __restrict__ WK,
    const float* __restrict__ WV, const float* __restrict__ WO,
    bf16* __restrict__ Xin, bf16* __restrict__ Wt) {
  __shared__ bf16 t[64][65];
  const int bx = blockIdx.x;
  const int tid = threadIdx.x;
  if (bx < 2048) {
    const int i = (bx * 256 + tid) * 8;
    float4 a = *reinterpret_cast<const float4*>(inputs + i);
    float4 b = *reinterpret_cast<const float4*>(inputs + i + 4);
    bf16x8 o;
    o[0] = (bf16)a.x; o[1] = (bf16)a.y; o[2] = (bf16)a.z; o[3] = (bf16)a.w;
    o[4] = (bf16)b.x; o[5] = (bf16)b.y; o[6] = (bf16)b.z; o[7] = (bf16)b.w;
    *reinterpret_cast<bf16x8*>(Xin + i) = o;
    return;
  }
  const int rr0 = bx - 2048;            // 0..1023
  const int z = rr0 >> 8;               // weight index
  const int tt = rr0 & 255;
  const int r0 = (tt >> 4) * 64, c0 = (tt & 15) * 64;
  const float* in = (z == 0) ? WQ : (z == 1) ? WK : (z == 2) ? WV : WO;
  bf16* op = Wt + (size_t)z * 1024 * 1024;
  const int rr = tid >> 3, cc = (tid & 7) * 8;
#pragma unroll
  for (int it = 0; it < 2; ++it) {
    int row = rr + it * 32;
    const float* ip = in + (size_t)(r0 + row) * 1024 + c0 + cc;
    float4 a = *reinterpret_cast<const float4*>(ip);
    float4 b = *reinterpret_cast<const float4*>(ip + 4);
    t[row][cc + 0] = (bf16)a.x; t[row][cc + 1] = (bf16)a.y;
    t[row][cc + 2] = (bf16)a.z; t[row][cc + 3] = (bf16)a.w;
    t[row][cc + 4] = (bf16)b.x; t[row][cc + 5] = (bf16)b.y;
    t[row][cc + 6] = (bf16)b.z; t[row][cc + 7] = (bf16)b.w;
  }
  __syncthreads();
#pragma unroll
  for (int it = 0; it < 2; ++it) {
    int crow = rr + it * 32;
    alignas(16) bf16 o[8];
#pragma unroll
    for (int e = 0; e < 8; ++e) o[e] = t[cc + e][crow];
    *reinterpret_cast<bf16x8*>(op + (size_t)(c0 + crow) * 1024 + r0 + cc) =
        *reinterpret_cast<bf16x8*>(o);
  }
}

// ---------------------------------------------------------------------------
// MTx128 bf16 MFMA GEMM (MT=128 or 64), BK=64, 4 waves (2x2).
// Staging: global_load_lds, linear LDS dest, pre-swizzled global source
// => LDS[row][x] = G[row][x^(row&7)]; reads use matching XOR -> 0 conflicts.
// EPI 0: scatter Katt(=q*KSCALE)/Qatt(=k) [bh][s][64]; VattT [bh][dv][S] packed.
// EPI 1: Cout[m][n] = acc + bOf[n] (fp32 out).
template <int EPI, int MT>
__global__ __launch_bounds__(256) void gemm128(
    const bf16* __restrict__ A, const bf16* __restrict__ Bt,
    const int M, const int N, const int K,
    bf16* __restrict__ Katt, bf16* __restrict__ Qatt, bf16* __restrict__ VattT,
    const float* __restrict__ bOf, float* __restrict__ Cout) {
  constexpr int MF = MT / 32;  // M-frags per wave (wr covers MT/2 rows)
  __shared__ bf16 As[MT * 64], Bs[8192];
  const int tid = threadIdx.x;
  const int lane = tid & 63;
  const int w = tid >> 6;
  const int wr = w >> 1, wc = w & 1;
  const int g = lane >> 4, c = lane & 15;
  const int m0 = blockIdx.y * MT, n0 = blockIdx.x * 128;
  const int sr = lane >> 3;                    // row within 8-row group
  const int scp = ((lane & 7) ^ sr) * 8;       // pre-swizzled source chunk

  f32x4 acc[MF][4];
#pragma unroll
  for (int i = 0; i < MF; ++i)
#pragma unroll
    for (int j = 0; j < 4; ++j) acc[i][j] = f32x4{0.f, 0.f, 0.f, 0.f};

  for (int k0 = 0; k0 < K; k0 += 64) {
#pragma unroll
    for (int p = 0; p < MT / 32; ++p) {
      const int rowb = p * 32 + w * 8;  // rowb%8==0 -> staged row&7 == sr
      gload_lds16(A + (size_t)(m0 + rowb + sr) * K + k0 + scp, &As[rowb * 64]);
    }
#pragma unroll
    for (int p = 0; p < 4; ++p) {
      const int rowb = p * 32 + w * 8;
      gload_lds16(Bt + (size_t)(n0 + rowb + sr) * K + k0 + scp, &Bs[rowb * 64]);
    }
    __syncthreads();  // drains vmcnt(0) before barrier -> tiles visible
#pragma unroll
    for (int kk = 0; kk < 2; ++kk) {
      const int ch = kk * 4 + g;
      bf16x8 af[MF], bfr[4];
#pragma unroll
      for (int mf = 0; mf < MF; ++mf) {
        const int row = wr * (MT / 2) + mf * 16 + c;
        af[mf] = *reinterpret_cast<const bf16x8*>(
            &As[row * 64 + ((ch ^ (row & 7)) << 3)]);
      }
#pragma unroll
      for (int nf = 0; nf < 4; ++nf) {
        const int row = wc * 64 + nf * 16 + c;
        bfr[nf] = *reinterpret_cast<const bf16x8*>(
            &Bs[row * 64 + ((ch ^ (row & 7)) << 3)]);
      }
#pragma unroll
      for (int mf = 0; mf < MF; ++mf)
#pragma unroll
        for (int nf = 0; nf < 4; ++nf)
          acc[mf][nf] = __builtin_amdgcn_mfma_f32_16x16x32_bf16(
              af[mf], bfr[nf], acc[mf][nf], 0, 0, 0);
    }
    __syncthreads();
  }

#pragma unroll
  for (int mf = 0; mf < MF; ++mf)
#pragma unroll
    for (int nf = 0; nf < 4; ++nf) {
      const int n = n0 + wc * 64 + nf * 16 + c;
      const int mb = m0 + wr * (MT / 2) + mf * 16 + g * 4;
      if (EPI == 0 && n >= 2048) {
        bf16x4 pk;
#pragma unroll
        for (int r = 0; r < 4; ++r) pk[r] = (bf16)acc[mf][nf][r];
        const int b = mb >> 11, sb = mb & (Sq - 1);
        const int h = (n >> 6) & 15, dk = n & 63;
        *reinterpret_cast<bf16x4*>(
            &VattT[((size_t)(b * Hh + h) * 64 + dk) * Sq + sb]) = pk;
      } else {
#pragma unroll
        for (int r = 0; r < 4; ++r) {
          const int m = mb + r;
          float v = acc[mf][nf][r];
          if (EPI == 0) {
            const int b = m >> 11, s = m & (Sq - 1);
            const int h = (n >> 6) & 15, dk = n & 63;
            const int bh = b * Hh + h;
            if (n < 1024)
              Katt[((size_t)bh * Sq + s) * 64 + dk] = (bf16)(v * KSCALE);
            else
              Qatt[((size_t)bh * Sq + s) * 64 + dk] = (bf16)v;
          } else {
            Cout[(size_t)m * N + n] = v + bOf[n];
          }
        }
      }
    }
}

// ---------------------------------------------------------------------------
// Causal flash attention v7. Q/K: [bh][S][64] bf16, Vt: [bh][64][S] bf16.
// QBLK=128: 4 waves, each wave owns 2 query-subtiles (rows w*16, 64+w*16) ->
// kf/vf LDS reads amortized over 2x MFMA work. K/V dbuf + reg prefetch,
// no-max softmax (p=2^s), deferred l-reduce, balanced qblk map. Grid 512.
__global__ __launch_bounds__(256, 2) void attn_v7(
    const bf16* __restrict__ Q, const bf16* __restrict__ K,
    const bf16* __restrict__ Vt, bf16* __restrict__ X) {
  __shared__ bf16 Kb[2][4096];
  __shared__ bf16 Vb[2][4096];
  __shared__ bf16 Pb[8192];  // wave w, subtile z owns [(w*2+z)*1024 ..)
  const int tid = threadIdx.x, lane = tid & 63, w = tid >> 6;
  const int g = lane >> 4, c = lane & 15;
  const int bx = blockIdx.x;
  const int u = bx >> 5;                       // 0..15
  const int bh = bx & 31;                      // bh%8 == bx%8 -> 4 heads/XCD
  const int um = (u + 4 * (bh >> 3)) & 15;
  const int qblk = (um < 8) ? um : 23 - um;    // balanced bijection per bh
  const int b = bh >> 4, h = bh & 15;
  const size_t base = (size_t)bh * Sq * 64;
  const bf16* Kg = K + base;
  const bf16* Vg = Vt + (size_t)bh * 64 * Sq;
  const int trow = tid >> 3, tch = tid & 7;

  // Q fragments straight from global (A-operand: row=c, k=kk*32+g*8+e)
  bf16x8 qf[2][2];
#pragma unroll
  for (int z = 0; z < 2; ++z) {
    const bf16* Qg = Q + base + ((size_t)qblk * 128 + z * 64 + w * 16 + c) * 64;
    qf[z][0] = *reinterpret_cast<const bf16x8*>(Qg + g * 8);
    qf[z][1] = *reinterpret_cast<const bf16x8*>(Qg + 32 + g * 8);
  }

  // stage K/V tile 0
#pragma unroll
  for (int pp = 0; pp < 2; ++pp) {
    int row = trow + pp * 32;
    *reinterpret_cast<bf16x8*>(&Kb[0][row * 64 + ((tch ^ (row & 7)) << 3)]) =
        *reinterpret_cast<const bf16x8*>(Kg + (size_t)row * 64 + tch * 8);
    *reinterpret_cast<bf16x8*>(&Vb[0][row * 64 + ((tch ^ (row & 7)) << 3)]) =
        *reinterpret_cast<const bf16x8*>(Vg + (size_t)row * Sq + tch * 8);
  }
  __syncthreads();

  f32x4 acc[2][4];
  float lpart[2][4];
#pragma unroll
  for (int z = 0; z < 2; ++z)
#pragma unroll
    for (int r = 0; r < 4; ++r) {
      lpart[z][r] = 0.f;
      acc[z][r] = f32x4{0.f, 0.f, 0.f, 0.f};
    }

  const int ntiles = 2 * qblk + 2;
  for (int t = 0; t < ntiles; ++t) {
    const int cur = t & 1;
    const bf16* Kc = Kb[cur];
    const bf16* Vc = Vb[cur];
    const bool hasnext = (t + 1 < ntiles);
    const bool act0 = (t != ntiles - 1);  // subtile 0 skips the last key tile

    // prefetch next K/V tile into registers (T14)
    bf16x8 kr0, kr1, vr0, vr1;
    if (hasnext) {
      const int i1 = (t + 1) * 64;
      kr0 = *reinterpret_cast<const bf16x8*>(Kg + (size_t)(i1 + trow) * 64 + tch * 8);
      kr1 = *reinterpret_cast<const bf16x8*>(Kg + (size_t)(i1 + trow + 32) * 64 + tch * 8);
      vr0 = *reinterpret_cast<const bf16x8*>(Vg + (size_t)trow * Sq + i1 + tch * 8);
      vr1 = *reinterpret_cast<const bf16x8*>(Vg + (size_t)(trow + 32) * Sq + i1 + tch * 8);
    }

    // S = Q K^T for both subtiles; kf loaded once, shared
    f32x4 sc[2][4];
#pragma unroll
    for (int z = 0; z < 2; ++z)
#pragma unroll
      for (int kg = 0; kg < 4; ++kg) sc[z][kg] = f32x4{0.f, 0.f, 0.f, 0.f};
#pragma unroll
    for (int kk = 0; kk < 2; ++kk) {
      const int ch = kk * 4 + g;
      bf16x8 kf[4];
#pragma unroll
      for (int kg = 0; kg < 4; ++kg) {
        int row = kg * 16 + c;
        kf[kg] = *reinterpret_cast<const bf16x8*>(
            &Kc[row * 64 + ((ch ^ (row & 7)) << 3)]);
      }
#pragma unroll
      for (int kg = 0; kg < 4; ++kg) {
        sc[1][kg] = __builtin_amdgcn_mfma_f32_16x16x32_bf16(
            qf[1][kk], kf[kg], sc[1][kg], 0, 0, 0);
        if (act0)
          sc[0][kg] = __builtin_amdgcn_mfma_f32_16x16x32_bf16(
              qf[0][kk], kf[kg], sc[0][kg], 0, 0, 0);
      }
    }

    // softmax-lite per subtile: p = 2^s, diag mask, P to LDS, partial sums
#pragma unroll
    for (int z = 0; z < 2; ++z) {
      if (z == 0 && !act0) continue;
      const bool diag = (z == 0) ? (t == ntiles - 2) : (t == ntiles - 1);
      bf16* Pz = Pb + (size_t)(w * 2 + z) * 1024;
#pragma unroll
      for (int kg = 0; kg < 4; ++kg)
#pragma unroll
        for (int r = 0; r < 4; ++r) {
          float p = __builtin_amdgcn_exp2f(sc[z][kg][r]);
          if (diag) {
            const int i = t * 64 + kg * 16 + c;
            const int j = qblk * 128 + z * 64 + w * 16 + g * 4 + r;
            p = (i <= j) ? p : 0.f;
          }
          lpart[z][r] += p;
          const int prow = g * 4 + r, pcol = kg * 16 + c;
          Pz[prow * 64 + (((pcol >> 3) ^ (prow & 7)) << 3) + (pcol & 7)] = (bf16)p;
        }
    }

    // O += P V for both subtiles; vf loaded once, shared
#pragma unroll
    for (int ks = 0; ks < 2; ++ks) {
      const int ch = ks * 4 + g;
      bf16x8 pf1 = *reinterpret_cast<const bf16x8*>(
          &Pb[(size_t)(w * 2 + 1) * 1024 + c * 64 + ((ch ^ (c & 7)) << 3)]);
      bf16x8 pf0;
      if (act0)
        pf0 = *reinterpret_cast<const bf16x8*>(
            &Pb[(size_t)(w * 2 + 0) * 1024 + c * 64 + ((ch ^ (c & 7)) << 3)]);
#pragma unroll
      for (int vg = 0; vg < 4; ++vg) {
        int dv = vg * 16 + c;
        bf16x8 vf = *reinterpret_cast<const bf16x8*>(
            &Vc[dv * 64 + ((ch ^ (dv & 7)) << 3)]);
        acc[1][vg] = __builtin_amdgcn_mfma_f32_16x16x32_bf16(
            pf1, vf, acc[1][vg], 0, 0, 0);
        if (act0)
          acc[0][vg] = __builtin_amdgcn_mfma_f32_16x16x32_bf16(
              pf0, vf, acc[0][vg], 0, 0, 0);
      }
    }

    // write prefetched tile into the idle buffer
    if (hasnext) {
      bf16* Kn = Kb[cur ^ 1];
      bf16* Vn = Vb[cur ^ 1];
      const int row0 = trow, row1 = trow + 32;
      *reinterpret_cast<bf16x8*>(&Kn[row0 * 64 + ((tch ^ (row0 & 7)) << 3)]) = kr0;
      *reinterpret_cast<bf16x8*>(&Kn[row1 * 64 + ((tch ^ (row1 & 7)) << 3)]) = kr1;
      *reinterpret_cast<bf16x8*>(&Vn[row0 * 64 + ((tch ^ (row0 & 7)) << 3)]) = vr0;
      *reinterpret_cast<bf16x8*>(&Vn[row1 * 64 + ((tch ^ (row1 & 7)) << 3)]) = vr1;
    }
    __syncthreads();
  }

  // deferred l-reduction (once) and output, per subtile
#pragma unroll
  for (int z = 0; z < 2; ++z) {
    float linv[4];
#pragma unroll
    for (int r = 0; r < 4; ++r) {
      float l = lpart[z][r];
      l += __shfl_xor(l, 1);
      l += __shfl_xor(l, 2);
      l += __shfl_xor(l, 4);
      l += __shfl_xor(l, 8);
      linv[r] = 1.f / l;
    }
#pragma unroll
    for (int vg = 0; vg < 4; ++vg)
#pragma unroll
      for (int r = 0; r < 4; ++r) {
        const int j = qblk * 128 + z * 64 + w * 16 + g * 4 + r;
        const int dv = vg * 16 + c;
        X[((size_t)b * Sq + j) * Dm + h * 64 + dv] = (bf16)(acc[z][vg][r] * linv[r]);
      }
  }
}

// ---------------------------------------------------------------------------
extern "C" void kernel_launch(void* const* d_in, const int* in_sizes, int n_in,
                              void* d_out, int out_size, void* d_ws, size_t ws_size,
                              hipStream_t stream) {
  const float* inputs = (const float*)d_in[0];
  // d_in[1] = mask: structural causal triu, recomputed analytically (unused)
  const float* WQ = (const float*)d_in[2];
  const float* WK = (const float*)d_in[3];
  const float* WV = (const float*)d_in[4];
  const float* WO = (const float*)d_in[5];
  const float* bO = (const float*)d_in[6];
  float* out = (float*)d_out;

  bf16* Xin   = (bf16*)d_ws;               // [4096][1024]; reused as X later
  bf16* Wt    = Xin + 4096 * 1024;         // [4096][1024]: WQt,WKt,WVt,WOt
  bf16* Katt  = Wt + 4 * 1024 * 1024;      // [32][2048][64]  (= q-proj * KSCALE)
  bf16* Qatt  = Katt + (1 << 22);          // [32][2048][64]  (= k-proj)
  bf16* VattT = Qatt + (1 << 22);          // [32][64][2048]  (= v-proj, transposed)
  bf16* X     = Xin;                       // alias: Xin dead after QKV GEMM
  // ws use: 40 MiB

  prep<<<3072, 256, 0, stream>>>(inputs, WQ, WK, WV, WO, Xin, Wt);

  gemm128<0, 128><<<dim3(24, 32), 256, 0, stream>>>(
      Xin, Wt, 4096, 3072, 1024, Katt, Qatt, VattT, nullptr, nullptr);

  attn_v7<<<dim3(512), 256, 0, stream>>>(Qatt, Katt, VattT, X);

  gemm128<1, 64><<<dim3(8, 64), 256, 0, stream>>>(
      X, Wt + 3 * 1024 * 1024, 4096, 1024, 1024,
      nullptr, nullptr, nullptr, bO, out);
}